// Round 15
// baseline (226.651 us; speedup 1.0000x reference)
//
#include <hip/hip_runtime.h>
#include <hip/hip_bf16.h>

#define FIN 128
#define HC 256
#define H1 4
#define C1 64
#define OUT2 16

typedef __attribute__((ext_vector_type(8))) short bf16x8;
typedef __attribute__((ext_vector_type(4))) float f32x4;
typedef __attribute__((ext_vector_type(4))) unsigned int uint32x4;

__device__ inline float bf2f(unsigned short u) {
    union { unsigned int i; float f; } v; v.i = ((unsigned int)u) << 16; return v.f;
}
__device__ inline unsigned short f2bf(float f) {
    union { float f; unsigned int i; } v; v.f = f;
    unsigned int i = v.i;
    return (unsigned short)((i + 0x7FFFu + ((i >> 16) & 1u)) >> 16);
}
__device__ inline unsigned int pack2(float a, float b) {
    return (unsigned int)f2bf(a) | ((unsigned int)f2bf(b) << 16);
}

// ------------- prep: W1 transpose to bf16 (blocks 0..127) + dst histogram -------------
__global__ __launch_bounds__(256) void prep_kernel(
    const float* __restrict__ W1, unsigned short* __restrict__ W1t,
    const int* __restrict__ dst, int* __restrict__ counts, int E)
{
    int b = blockIdx.x;
    if (b < 128) {
        int t = b * 256 + threadIdx.x;   // 32768 = HC*FIN
        int c = t >> 7, k = t & 127;
        W1t[t] = f2bf(W1[k * HC + c]);
    } else {
        int e = (b - 128) * 256 + threadIdx.x;
        if (e < E) atomicAdd(&counts[dst[e]], 1);
    }
}

// ------------- GEMM1 via MFMA bf16, fused layer-1 attention dots -------------
__global__ __launch_bounds__(256) void gemm1_mfma_kernel(
    const float* __restrict__ x, const unsigned short* __restrict__ W1t,
    const float* __restrict__ att_src, const float* __restrict__ att_dst,
    unsigned short* __restrict__ h1, float* __restrict__ a_src,
    float* __restrict__ a_dst, int N)
{
    const int t  = threadIdx.x;
    const int wv = t >> 6;
    const int l  = t & 63;
    const int c0 = l & 15;
    const int h  = l >> 4;
    const int R0 = blockIdx.x * 64 + wv * 16;

    f32x4 acc[16];
    #pragma unroll
    for (int j = 0; j < 16; j++) acc[j] = (f32x4){0.f, 0.f, 0.f, 0.f};

    int arow = R0 + c0;
    if (arow > N - 1) arow = N - 1;        // clamp loads; stores are guarded
    const float* xrow = x + (size_t)arow * FIN;

    for (int kb = 0; kb < FIN; kb += 32) {
        float4 f0 = *(const float4*)&xrow[kb + 8 * h];
        float4 f1 = *(const float4*)&xrow[kb + 8 * h + 4];
        union { bf16x8 v; unsigned int u[4]; } af;
        af.u[0] = pack2(f0.x, f0.y);
        af.u[1] = pack2(f0.z, f0.w);
        af.u[2] = pack2(f1.x, f1.y);
        af.u[3] = pack2(f1.z, f1.w);
        #pragma unroll
        for (int j = 0; j < 16; j++) {
            int col = 16 * j + c0;
            union { bf16x8 v; uint4 u; } bf;
            bf.u = *(const uint4*)&W1t[(size_t)col * FIN + kb + 8 * h];
            acc[j] = __builtin_amdgcn_mfma_f32_16x16x32_bf16(af.v, bf.v, acc[j], 0, 0, 0);
        }
    }

    // ---- fused attention dots
    float avs[16], avd[16];
    #pragma unroll
    for (int j = 0; j < 16; j++) {
        avs[j] = att_src[16 * j + c0];
        avd[j] = att_dst[16 * j + c0];
    }
    f32x4 ps[4], pd[4];
    #pragma unroll
    for (int hd = 0; hd < 4; hd++) {
        ps[hd] = (f32x4){0.f, 0.f, 0.f, 0.f};
        pd[hd] = (f32x4){0.f, 0.f, 0.f, 0.f};
        #pragma unroll
        for (int jj = 0; jj < 4; jj++) {
            int j = 4 * hd + jj;
            #pragma unroll
            for (int r = 0; r < 4; r++) {
                ps[hd][r] = fmaf(acc[j][r], avs[j], ps[hd][r]);
                pd[hd][r] = fmaf(acc[j][r], avd[j], pd[hd][r]);
            }
        }
    }
    #pragma unroll
    for (int hd = 0; hd < 4; hd++)
        #pragma unroll
        for (int r = 0; r < 4; r++) {
            float s = ps[hd][r], d = pd[hd][r];
            s += __shfl_xor(s, 1, 64);  d += __shfl_xor(d, 1, 64);
            s += __shfl_xor(s, 2, 64);  d += __shfl_xor(d, 2, 64);
            s += __shfl_xor(s, 4, 64);  d += __shfl_xor(d, 4, 64);
            s += __shfl_xor(s, 8, 64);  d += __shfl_xor(d, 8, 64);
            ps[hd][r] = s;  pd[hd][r] = d;
        }
    {
        float s_sel = 0.f, d_sel = 0.f;
        #pragma unroll
        for (int hd = 0; hd < 4; hd++)
            #pragma unroll
            for (int r = 0; r < 4; r++) {
                bool m = (c0 == hd * 4 + r);
                s_sel = m ? ps[hd][r] : s_sel;
                d_sel = m ? pd[hd][r] : d_sel;
            }
        int row = R0 + 4 * h + (c0 & 3);
        if (row < N) {
            a_src[row * 4 + (c0 >> 2)] = s_sel;
            a_dst[row * 4 + (c0 >> 2)] = d_sel;
        }
    }

    // ---- h1 store (bf16)
    #pragma unroll
    for (int r = 0; r < 4; r++) {
        int row = R0 + 4 * h + r;
        if (row < N) {
            unsigned short* hp = &h1[(size_t)row * HC + c0];
            #pragma unroll
            for (int j = 0; j < 16; j++)
                hp[16 * j] = f2bf(acc[j][r]);
        }
    }
}

// ---------------- CSR scan (block offsets folded into consumers) ----------------
__global__ __launch_bounds__(1024) void scan1_kernel(
    const int* __restrict__ counts, int* __restrict__ rowptr,
    int* __restrict__ bsum, int n)
{
    __shared__ int sm[1024];
    int tid = threadIdx.x;
    int i = blockIdx.x * 1024 + tid;
    int v = (i < n) ? counts[i] : 0;
    sm[tid] = v;
    __syncthreads();
    for (int off = 1; off < 1024; off <<= 1) {
        int tv = (tid >= off) ? sm[tid - off] : 0;
        __syncthreads();
        sm[tid] += tv;
        __syncthreads();
    }
    if (i < n) rowptr[i] = sm[tid] - v;    // block-local exclusive
    if (tid == 1023) bsum[blockIdx.x] = sm[1023];
}

__global__ __launch_bounds__(1024) void scan2_kernel(
    int* __restrict__ bsum, int nb)
{
    __shared__ int sm[1024];
    int tid = threadIdx.x;
    int v = (tid < nb) ? bsum[tid] : 0;
    sm[tid] = v;
    __syncthreads();
    for (int off = 1; off < 1024; off <<= 1) {
        int tv = (tid >= off) ? sm[tid - off] : 0;
        __syncthreads();
        sm[tid] += tv;
        __syncthreads();
    }
    if (tid < nb) bsum[tid] = sm[tid] - v;  // exclusive block offsets
}

// scatter: single packed 16B record {src, dst, w01(bf16x2), w23(bf16x2)}
__global__ __launch_bounds__(256) void scatter_kernel(
    const int* __restrict__ src, const int* __restrict__ dst,
    const int* __restrict__ rowptr, const int* __restrict__ bsum,
    int* __restrict__ cursor,
    const float* __restrict__ a_src, const float* __restrict__ a_dst,
    uint4* __restrict__ csr_rec, int E)
{
    int e = blockIdx.x * blockDim.x + threadIdx.x;
    if (e >= E) return;
    int s = src[e], d = dst[e];
    int pos = rowptr[d] + bsum[d >> 10] + atomicAdd(&cursor[d], 1);
    float4 av = *(const float4*)&a_src[(size_t)s * 4];
    float4 bv = *(const float4*)&a_dst[(size_t)d * 4];
    float w0, w1, w2, w3, v;
    v = av.x + bv.x; v = v > 0.f ? v : 0.2f * v; w0 = __expf(v);
    v = av.y + bv.y; v = v > 0.f ? v : 0.2f * v; w1 = __expf(v);
    v = av.z + bv.z; v = v > 0.f ? v : 0.2f * v; w2 = __expf(v);
    v = av.w + bv.w; v = v > 0.f ? v : 0.2f * v; w3 = __expf(v);
    uint4 rec;
    rec.x = (unsigned int)s;
    rec.y = (unsigned int)d;
    rec.z = pack2(w0, w1);
    rec.w = pack2(w2, w3);
    csr_rec[pos] = rec;
}

// ------------- aggregate layer1 + bias + relu + fused gemm2 + layer-2 att dots -------------
// csr_rec read NONTEMPORAL (single-use stream; keep L2 ways for h1 gather).
__global__ __launch_bounds__(256) void agg1_kernel(
    const unsigned short* __restrict__ h1,
    const uint32x4* __restrict__ csr_rec, const int* __restrict__ rowptr,
    const int* __restrict__ bsum,
    const float* __restrict__ b1, const float* __restrict__ W2,
    const float* __restrict__ att_src2, const float* __restrict__ att_dst2,
    float* __restrict__ h2, float* __restrict__ a_src2, float* __restrict__ a_dst2,
    int N, int E)
{
    __shared__ float o_sh[4][272];   // idx = k + 4*(k>>6): q-groups land in distinct banks
    int wave = (int)((blockIdx.x * blockDim.x + threadIdx.x) >> 6);
    if (wave >= N) return;
    int node = __builtin_amdgcn_readfirstlane(wave);
    int wv = (threadIdx.x >> 6);
    int l = threadIdx.x & 63;
    int h = l >> 4;
    int rs = rowptr[node] + bsum[node >> 10];
    int re = (node + 1 == N) ? E : rowptr[node + 1] + bsum[(node + 1) >> 10];
    float a0 = 0.f, a1 = 0.f, a2 = 0.f, a3 = 0.f, sw = 0.f;
    int p = rs;
    for (; p + 8 <= re; p += 8) {
        uint32x4 r[8];
        #pragma unroll
        for (int j = 0; j < 8; j++) r[j] = __builtin_nontemporal_load(&csr_rec[p + j]);
        uint2 hv[8];
        #pragma unroll
        for (int j = 0; j < 8; j++)
            hv[j] = *(const uint2*)&h1[(size_t)(int)r[j].x * HC + 4 * l];
        #pragma unroll
        for (int j = 0; j < 8; j++) {
            unsigned int wsel = (h & 2) ? r[j].w : r[j].z;
            float wv_ = bf2f((unsigned short)((h & 1) ? (wsel >> 16) : (wsel & 0xffff)));
            a0 = fmaf(wv_, bf2f((unsigned short)(hv[j].x & 0xffff)), a0);
            a1 = fmaf(wv_, bf2f((unsigned short)(hv[j].x >> 16)), a1);
            a2 = fmaf(wv_, bf2f((unsigned short)(hv[j].y & 0xffff)), a2);
            a3 = fmaf(wv_, bf2f((unsigned short)(hv[j].y >> 16)), a3);
            sw += wv_;
        }
    }
    for (; p < re; p++) {
        uint32x4 r = __builtin_nontemporal_load(&csr_rec[p]);
        uint2 hv = *(const uint2*)&h1[(size_t)(int)r.x * HC + 4 * l];
        unsigned int wsel = (h & 2) ? r.w : r.z;
        float wv_ = bf2f((unsigned short)((h & 1) ? (wsel >> 16) : (wsel & 0xffff)));
        a0 = fmaf(wv_, bf2f((unsigned short)(hv.x & 0xffff)), a0);
        a1 = fmaf(wv_, bf2f((unsigned short)(hv.x >> 16)), a1);
        a2 = fmaf(wv_, bf2f((unsigned short)(hv.y & 0xffff)), a2);
        a3 = fmaf(wv_, bf2f((unsigned short)(hv.y >> 16)), a3);
        sw += wv_;
    }
    float inv = 1.f / (sw + 1e-16f);
    float4 bv = *(const float4*)&b1[4 * l];
    float o0 = fmaxf(a0 * inv + bv.x, 0.f);
    float o1 = fmaxf(a1 * inv + bv.y, 0.f);
    float o2 = fmaxf(a2 * inv + bv.z, 0.f);
    float o3 = fmaxf(a3 * inv + bv.w, 0.f);

    // ---- fused gemm2 via wave-private LDS (k = 4l..4l+3 stored at k + 4*(k>>6))
    float* my = o_sh[wv];
    *(float4*)&my[4 * l + 4 * h] = make_float4(o0, o1, o2, o3);
    asm volatile("s_waitcnt lgkmcnt(0)" ::: "memory");
    __builtin_amdgcn_sched_barrier(0);
    int q = h;        // l>>4
    int c = l & 15;
    float part = 0.f;
    #pragma unroll
    for (int m = 0; m < 16; m++) {
        float4 ov = *(const float4*)&my[68 * q + 4 * m];
        const float* w = &W2[(size_t)(64 * q + 4 * m) * OUT2 + c];
        part = fmaf(ov.x, w[0],  part);
        part = fmaf(ov.y, w[16], part);
        part = fmaf(ov.z, w[32], part);
        part = fmaf(ov.w, w[48], part);
    }
    part += __shfl_xor(part, 16, 64);
    part += __shfl_xor(part, 32, 64);
    // all lanes hold h2[node][c]
    float ps = part * att_src2[c];
    float pdv = part * att_dst2[c];
    ps += __shfl_xor(ps, 1, 64);  pdv += __shfl_xor(pdv, 1, 64);
    ps += __shfl_xor(ps, 2, 64);  pdv += __shfl_xor(pdv, 2, 64);
    ps += __shfl_xor(ps, 4, 64);  pdv += __shfl_xor(pdv, 4, 64);
    ps += __shfl_xor(ps, 8, 64);  pdv += __shfl_xor(pdv, 8, 64);
    if (l == 0) { a_src2[node] = ps; a_dst2[node] = pdv; }
    if (l < 16) h2[(size_t)node * OUT2 + l] = part;
}

// ------------- aggregate layer2 (inline edge weights) + bias -> out, unroll x4 -------------
__global__ __launch_bounds__(256) void agg2_kernel(
    const float* __restrict__ h2,
    const int* __restrict__ csr_rec_i,
    const float* __restrict__ a_src2, const float* __restrict__ a_dst2,
    const int* __restrict__ rowptr, const int* __restrict__ bsum,
    const float* __restrict__ b2, float* __restrict__ out, int N, int E)
{
    int wave = (int)((blockIdx.x * blockDim.x + threadIdx.x) >> 6);
    if (wave >= N) return;
    int node = __builtin_amdgcn_readfirstlane(wave);
    int l = threadIdx.x & 63;
    int g = l >> 4, c = l & 15;
    int rs = rowptr[node] + bsum[node >> 10];
    int re = (node + 1 == N) ? E : rowptr[node + 1] + bsum[(node + 1) >> 10];
    float ad = a_dst2[node];
    float acc = 0.f, sw = 0.f;
    int p = rs + g;
    for (; p + 12 < re; p += 16) {
        int sn0 = __builtin_nontemporal_load(&csr_rec_i[(size_t)(p     ) * 4]);
        int sn1 = __builtin_nontemporal_load(&csr_rec_i[(size_t)(p +  4) * 4]);
        int sn2 = __builtin_nontemporal_load(&csr_rec_i[(size_t)(p +  8) * 4]);
        int sn3 = __builtin_nontemporal_load(&csr_rec_i[(size_t)(p + 12) * 4]);
        float e0 = a_src2[sn0] + ad;
        float e1 = a_src2[sn1] + ad;
        float e2 = a_src2[sn2] + ad;
        float e3 = a_src2[sn3] + ad;
        float x0 = h2[(size_t)sn0 * OUT2 + c];
        float x1 = h2[(size_t)sn1 * OUT2 + c];
        float x2 = h2[(size_t)sn2 * OUT2 + c];
        float x3 = h2[(size_t)sn3 * OUT2 + c];
        e0 = e0 > 0.f ? e0 : 0.2f * e0;
        e1 = e1 > 0.f ? e1 : 0.2f * e1;
        e2 = e2 > 0.f ? e2 : 0.2f * e2;
        e3 = e3 > 0.f ? e3 : 0.2f * e3;
        float w0 = __expf(e0), w1 = __expf(e1), w2 = __expf(e2), w3 = __expf(e3);
        acc = fmaf(w0, x0, acc);
        acc = fmaf(w1, x1, acc);
        acc = fmaf(w2, x2, acc);
        acc = fmaf(w3, x3, acc);
        sw += (w0 + w1) + (w2 + w3);
    }
    for (; p < re; p += 4) {
        int sn = __builtin_nontemporal_load(&csr_rec_i[(size_t)p * 4]);
        float e0 = a_src2[sn] + ad;
        e0 = e0 > 0.f ? e0 : 0.2f * e0;
        float w0 = __expf(e0);
        acc = fmaf(w0, h2[(size_t)sn * OUT2 + c], acc);
        sw += w0;
    }
    acc += __shfl_xor(acc, 16, 64);
    acc += __shfl_xor(acc, 32, 64);
    sw += __shfl_xor(sw, 16, 64);
    sw += __shfl_xor(sw, 32, 64);
    if (l < 16)
        out[(size_t)node * OUT2 + l] = acc / (sw + 1e-16f) + b2[l];
}

extern "C" void kernel_launch(void* const* d_in, const int* in_sizes, int n_in,
                              void* d_out, int out_size, void* d_ws, size_t ws_size,
                              hipStream_t stream)
{
    const float* x        = (const float*)d_in[0];
    const int*   ei       = (const int*)d_in[1];
    const float* W1       = (const float*)d_in[2];
    const float* att_src1 = (const float*)d_in[3];
    const float* att_dst1 = (const float*)d_in[4];
    const float* b1       = (const float*)d_in[5];
    const float* W2       = (const float*)d_in[6];
    const float* att_src2 = (const float*)d_in[7];
    const float* att_dst2 = (const float*)d_in[8];
    const float* b2       = (const float*)d_in[9];
    float* out = (float*)d_out;

    const int N = in_sizes[0] / FIN;
    const int E = in_sizes[1] / 2;
    const int* srcv = ei;
    const int* dstv = ei + E;

    char* base = (char*)d_ws;
    #define ALLOC(ptr, type, nelem) \
        type* ptr = (type*)base; base += (((size_t)(nelem) * sizeof(type) + 255) & ~(size_t)255);
    ALLOC(h1,      unsigned short, (size_t)N * HC)
    ALLOC(csr_rec, uint4,          (size_t)E)
    ALLOC(h2,      float,          (size_t)N * OUT2)
    ALLOC(a_src1v, float,          (size_t)N * 4)
    ALLOC(a_dst1v, float,          (size_t)N * 4)
    ALLOC(a_src2v, float,          (size_t)N)
    ALLOC(a_dst2v, float,          (size_t)N)
    ALLOC(counts,  int,            (size_t)2 * N)      // counts + cursor adjacent
    ALLOC(rowptr,  int,            (size_t)N + 1)
    ALLOC(bsum,    int,            1024)
    #undef ALLOC
    int* cursor = counts + N;
    // W1t (64 KB) aliases the head of csr_rec: live only between prep_kernel and
    // gemm1_mfma_kernel; csr_rec is written later by scatter_kernel.
    unsigned short* W1t = (unsigned short*)csr_rec;

    const int nb = (N + 1023) / 1024;

    (void)hipMemsetAsync(counts, 0, sizeof(int) * 2 * (size_t)N, stream);

    prep_kernel<<<128 + (E + 255) / 256, 256, 0, stream>>>(W1, W1t, dstv, counts, E);
    gemm1_mfma_kernel<<<(N + 63) / 64, 256, 0, stream>>>(x, W1t, att_src1, att_dst1,
                                                         h1, a_src1v, a_dst1v, N);
    scan1_kernel<<<nb, 1024, 0, stream>>>(counts, rowptr, bsum, N);
    scan2_kernel<<<1, 1024, 0, stream>>>(bsum, nb);
    scatter_kernel<<<(E + 255) / 256, 256, 0, stream>>>(srcv, dstv, rowptr, bsum, cursor,
                                                        a_src1v, a_dst1v, csr_rec, E);
    agg1_kernel<<<(N + 3) / 4, 256, 0, stream>>>(h1, (const uint32x4*)csr_rec,
                                                 rowptr, bsum, b1, W2,
                                                 att_src2, att_dst2,
                                                 h2, a_src2v, a_dst2v, N, E);
    agg2_kernel<<<(N + 3) / 4, 256, 0, stream>>>(h2, (const int*)csr_rec,
                                                 a_src2v, a_dst2v, rowptr, bsum,
                                                 b2, out, N, E);
}

// Round 16
// 204.069 us; speedup vs baseline: 1.1107x; 1.1107x over previous
//
#include <hip/hip_runtime.h>
#include <hip/hip_bf16.h>

#define FIN 128
#define HC 256
#define H1 4
#define C1 64
#define OUT2 16

typedef __attribute__((ext_vector_type(8))) short bf16x8;
typedef __attribute__((ext_vector_type(4))) float f32x4;

__device__ inline float bf2f(unsigned short u) {
    union { unsigned int i; float f; } v; v.i = ((unsigned int)u) << 16; return v.f;
}
__device__ inline unsigned short f2bf(float f) {
    union { float f; unsigned int i; } v; v.f = f;
    unsigned int i = v.i;
    return (unsigned short)((i + 0x7FFFu + ((i >> 16) & 1u)) >> 16);
}
__device__ inline unsigned int pack2(float a, float b) {
    return (unsigned int)f2bf(a) | ((unsigned int)f2bf(b) << 16);
}

// ------------- W1 transpose to bf16: W1t[col][k] = bf16(W1[k][col]) -------------
__global__ __launch_bounds__(256) void w1t_kernel(
    const float* __restrict__ W1, unsigned short* __restrict__ W1t)
{
    int t = blockIdx.x * 256 + threadIdx.x;   // 32768 = HC*FIN
    int c = t >> 7, k = t & 127;
    W1t[t] = f2bf(W1[k * HC + c]);
}

// ------------- GEMM1 via MFMA bf16 + fused layer-1 att dots; extra blocks do dst histogram -------------
// gemm blocks: 4 waves x 16 rows; A row=lane&15, k=8*(lane>>4)+e; B col=lane&15; D col=lane&15,row=4*(lane>>4)+r
__global__ __launch_bounds__(256) void gemm1_hist_kernel(
    const float* __restrict__ x, const unsigned short* __restrict__ W1t,
    const float* __restrict__ att_src, const float* __restrict__ att_dst,
    unsigned short* __restrict__ h1, float* __restrict__ a_src,
    float* __restrict__ a_dst, int N, int gemmBlocks,
    const int* __restrict__ dst, int* __restrict__ counts, int E)
{
    if (blockIdx.x >= gemmBlocks) {
        // ---- dst histogram (independent of gemm; overlaps it) ----
        int e = (blockIdx.x - gemmBlocks) * 256 + threadIdx.x;
        if (e < E) atomicAdd(&counts[dst[e]], 1);
        return;
    }
    const int t  = threadIdx.x;
    const int wv = t >> 6;
    const int l  = t & 63;
    const int c0 = l & 15;
    const int h  = l >> 4;
    const int R0 = blockIdx.x * 64 + wv * 16;

    f32x4 acc[16];
    #pragma unroll
    for (int j = 0; j < 16; j++) acc[j] = (f32x4){0.f, 0.f, 0.f, 0.f};

    int arow = R0 + c0;
    if (arow > N - 1) arow = N - 1;        // clamp loads; stores are guarded
    const float* xrow = x + (size_t)arow * FIN;

    for (int kb = 0; kb < FIN; kb += 32) {
        float4 f0 = *(const float4*)&xrow[kb + 8 * h];
        float4 f1 = *(const float4*)&xrow[kb + 8 * h + 4];
        union { bf16x8 v; unsigned int u[4]; } af;
        af.u[0] = pack2(f0.x, f0.y);
        af.u[1] = pack2(f0.z, f0.w);
        af.u[2] = pack2(f1.x, f1.y);
        af.u[3] = pack2(f1.z, f1.w);
        #pragma unroll
        for (int j = 0; j < 16; j++) {
            int col = 16 * j + c0;
            union { bf16x8 v; uint4 u; } bf;
            bf.u = *(const uint4*)&W1t[(size_t)col * FIN + kb + 8 * h];
            acc[j] = __builtin_amdgcn_mfma_f32_16x16x32_bf16(af.v, bf.v, acc[j], 0, 0, 0);
        }
    }

    // ---- fused attention dots
    float avs[16], avd[16];
    #pragma unroll
    for (int j = 0; j < 16; j++) {
        avs[j] = att_src[16 * j + c0];
        avd[j] = att_dst[16 * j + c0];
    }
    f32x4 ps[4], pd[4];
    #pragma unroll
    for (int hd = 0; hd < 4; hd++) {
        ps[hd] = (f32x4){0.f, 0.f, 0.f, 0.f};
        pd[hd] = (f32x4){0.f, 0.f, 0.f, 0.f};
        #pragma unroll
        for (int jj = 0; jj < 4; jj++) {
            int j = 4 * hd + jj;
            #pragma unroll
            for (int r = 0; r < 4; r++) {
                ps[hd][r] = fmaf(acc[j][r], avs[j], ps[hd][r]);
                pd[hd][r] = fmaf(acc[j][r], avd[j], pd[hd][r]);
            }
        }
    }
    #pragma unroll
    for (int hd = 0; hd < 4; hd++)
        #pragma unroll
        for (int r = 0; r < 4; r++) {
            float s = ps[hd][r], d = pd[hd][r];
            s += __shfl_xor(s, 1, 64);  d += __shfl_xor(d, 1, 64);
            s += __shfl_xor(s, 2, 64);  d += __shfl_xor(d, 2, 64);
            s += __shfl_xor(s, 4, 64);  d += __shfl_xor(d, 4, 64);
            s += __shfl_xor(s, 8, 64);  d += __shfl_xor(d, 8, 64);
            ps[hd][r] = s;  pd[hd][r] = d;
        }
    {
        float s_sel = 0.f, d_sel = 0.f;
        #pragma unroll
        for (int hd = 0; hd < 4; hd++)
            #pragma unroll
            for (int r = 0; r < 4; r++) {
                bool m = (c0 == hd * 4 + r);
                s_sel = m ? ps[hd][r] : s_sel;
                d_sel = m ? pd[hd][r] : d_sel;
            }
        int row = R0 + 4 * h + (c0 & 3);
        if (row < N) {
            a_src[row * 4 + (c0 >> 2)] = s_sel;
            a_dst[row * 4 + (c0 >> 2)] = d_sel;
        }
    }

    // ---- h1 store (bf16)
    #pragma unroll
    for (int r = 0; r < 4; r++) {
        int row = R0 + 4 * h + r;
        if (row < N) {
            unsigned short* hp = &h1[(size_t)row * HC + c0];
            #pragma unroll
            for (int j = 0; j < 16; j++)
                hp[16 * j] = f2bf(acc[j][r]);
        }
    }
}

// ---------------- CSR scan (block offsets folded into consumers) ----------------
__global__ __launch_bounds__(1024) void scan1_kernel(
    const int* __restrict__ counts, int* __restrict__ rowptr,
    int* __restrict__ bsum, int n)
{
    __shared__ int sm[1024];
    int tid = threadIdx.x;
    int i = blockIdx.x * 1024 + tid;
    int v = (i < n) ? counts[i] : 0;
    sm[tid] = v;
    __syncthreads();
    for (int off = 1; off < 1024; off <<= 1) {
        int tv = (tid >= off) ? sm[tid - off] : 0;
        __syncthreads();
        sm[tid] += tv;
        __syncthreads();
    }
    if (i < n) rowptr[i] = sm[tid] - v;    // block-local exclusive
    if (tid == 1023) bsum[blockIdx.x] = sm[1023];
}

__global__ __launch_bounds__(1024) void scan2_kernel(
    int* __restrict__ bsum, int nb)
{
    __shared__ int sm[1024];
    int tid = threadIdx.x;
    int v = (tid < nb) ? bsum[tid] : 0;
    sm[tid] = v;
    __syncthreads();
    for (int off = 1; off < 1024; off <<= 1) {
        int tv = (tid >= off) ? sm[tid - off] : 0;
        __syncthreads();
        sm[tid] += tv;
        __syncthreads();
    }
    if (tid < nb) bsum[tid] = sm[tid] - v;  // exclusive block offsets
}

// scatter: single packed 16B record {src, dst, w01(bf16x2), w23(bf16x2)}
__global__ __launch_bounds__(256) void scatter_kernel(
    const int* __restrict__ src, const int* __restrict__ dst,
    const int* __restrict__ rowptr, const int* __restrict__ bsum,
    int* __restrict__ cursor,
    const float* __restrict__ a_src, const float* __restrict__ a_dst,
    uint4* __restrict__ csr_rec, int E)
{
    int e = blockIdx.x * blockDim.x + threadIdx.x;
    if (e >= E) return;
    int s = src[e], d = dst[e];
    int pos = rowptr[d] + bsum[d >> 10] + atomicAdd(&cursor[d], 1);
    float4 av = *(const float4*)&a_src[(size_t)s * 4];
    float4 bv = *(const float4*)&a_dst[(size_t)d * 4];
    float w0, w1, w2, w3, v;
    v = av.x + bv.x; v = v > 0.f ? v : 0.2f * v; w0 = __expf(v);
    v = av.y + bv.y; v = v > 0.f ? v : 0.2f * v; w1 = __expf(v);
    v = av.z + bv.z; v = v > 0.f ? v : 0.2f * v; w2 = __expf(v);
    v = av.w + bv.w; v = v > 0.f ? v : 0.2f * v; w3 = __expf(v);
    uint4 rec;
    rec.x = (unsigned int)s;
    rec.y = (unsigned int)d;
    rec.z = pack2(w0, w1);
    rec.w = pack2(w2, w3);
    csr_rec[pos] = rec;
}

// ------------- aggregate layer1 + bias + relu + fused gemm2 + layer-2 att dots -------------
__global__ __launch_bounds__(256) void agg1_kernel(
    const unsigned short* __restrict__ h1,
    const uint4* __restrict__ csr_rec, const int* __restrict__ rowptr,
    const int* __restrict__ bsum,
    const float* __restrict__ b1, const float* __restrict__ W2,
    const float* __restrict__ att_src2, const float* __restrict__ att_dst2,
    float* __restrict__ h2, float* __restrict__ a_src2, float* __restrict__ a_dst2,
    int N, int E)
{
    __shared__ float o_sh[4][272];   // idx = k + 4*(k>>6): q-groups land in distinct banks
    int wave = (int)((blockIdx.x * blockDim.x + threadIdx.x) >> 6);
    if (wave >= N) return;
    int node = __builtin_amdgcn_readfirstlane(wave);
    int wv = (threadIdx.x >> 6);
    int l = threadIdx.x & 63;
    int h = l >> 4;
    int rs = rowptr[node] + bsum[node >> 10];
    int re = (node + 1 == N) ? E : rowptr[node + 1] + bsum[(node + 1) >> 10];
    float a0 = 0.f, a1 = 0.f, a2 = 0.f, a3 = 0.f, sw = 0.f;
    int p = rs;
    for (; p + 8 <= re; p += 8) {
        uint4 r[8];
        #pragma unroll
        for (int j = 0; j < 8; j++) r[j] = csr_rec[p + j];
        uint2 hv[8];
        #pragma unroll
        for (int j = 0; j < 8; j++)
            hv[j] = *(const uint2*)&h1[(size_t)(int)r[j].x * HC + 4 * l];
        #pragma unroll
        for (int j = 0; j < 8; j++) {
            unsigned int wsel = (h & 2) ? r[j].w : r[j].z;
            float wv_ = bf2f((unsigned short)((h & 1) ? (wsel >> 16) : (wsel & 0xffff)));
            a0 = fmaf(wv_, bf2f((unsigned short)(hv[j].x & 0xffff)), a0);
            a1 = fmaf(wv_, bf2f((unsigned short)(hv[j].x >> 16)), a1);
            a2 = fmaf(wv_, bf2f((unsigned short)(hv[j].y & 0xffff)), a2);
            a3 = fmaf(wv_, bf2f((unsigned short)(hv[j].y >> 16)), a3);
            sw += wv_;
        }
    }
    for (; p < re; p++) {
        uint4 r = csr_rec[p];
        uint2 hv = *(const uint2*)&h1[(size_t)(int)r.x * HC + 4 * l];
        unsigned int wsel = (h & 2) ? r.w : r.z;
        float wv_ = bf2f((unsigned short)((h & 1) ? (wsel >> 16) : (wsel & 0xffff)));
        a0 = fmaf(wv_, bf2f((unsigned short)(hv.x & 0xffff)), a0);
        a1 = fmaf(wv_, bf2f((unsigned short)(hv.x >> 16)), a1);
        a2 = fmaf(wv_, bf2f((unsigned short)(hv.y & 0xffff)), a2);
        a3 = fmaf(wv_, bf2f((unsigned short)(hv.y >> 16)), a3);
        sw += wv_;
    }
    float inv = 1.f / (sw + 1e-16f);
    float4 bv = *(const float4*)&b1[4 * l];
    float o0 = fmaxf(a0 * inv + bv.x, 0.f);
    float o1 = fmaxf(a1 * inv + bv.y, 0.f);
    float o2 = fmaxf(a2 * inv + bv.z, 0.f);
    float o3 = fmaxf(a3 * inv + bv.w, 0.f);

    // ---- fused gemm2 via wave-private LDS (k = 4l..4l+3 stored at k + 4*(k>>6))
    float* my = o_sh[wv];
    *(float4*)&my[4 * l + 4 * h] = make_float4(o0, o1, o2, o3);
    asm volatile("s_waitcnt lgkmcnt(0)" ::: "memory");
    __builtin_amdgcn_sched_barrier(0);
    int q = h;        // l>>4
    int c = l & 15;
    float part = 0.f;
    #pragma unroll
    for (int m = 0; m < 16; m++) {
        float4 ov = *(const float4*)&my[68 * q + 4 * m];
        const float* w = &W2[(size_t)(64 * q + 4 * m) * OUT2 + c];
        part = fmaf(ov.x, w[0],  part);
        part = fmaf(ov.y, w[16], part);
        part = fmaf(ov.z, w[32], part);
        part = fmaf(ov.w, w[48], part);
    }
    part += __shfl_xor(part, 16, 64);
    part += __shfl_xor(part, 32, 64);
    // all lanes hold h2[node][c]
    float ps = part * att_src2[c];
    float pdv = part * att_dst2[c];
    ps += __shfl_xor(ps, 1, 64);  pdv += __shfl_xor(pdv, 1, 64);
    ps += __shfl_xor(ps, 2, 64);  pdv += __shfl_xor(pdv, 2, 64);
    ps += __shfl_xor(ps, 4, 64);  pdv += __shfl_xor(pdv, 4, 64);
    ps += __shfl_xor(ps, 8, 64);  pdv += __shfl_xor(pdv, 8, 64);
    if (l == 0) { a_src2[node] = ps; a_dst2[node] = pdv; }
    if (l < 16) h2[(size_t)node * OUT2 + l] = part;
}

// ------------- aggregate layer2 (inline edge weights) + bias -> out, unroll x4 -------------
__global__ __launch_bounds__(256) void agg2_kernel(
    const float* __restrict__ h2,
    const int* __restrict__ csr_rec_i,
    const float* __restrict__ a_src2, const float* __restrict__ a_dst2,
    const int* __restrict__ rowptr, const int* __restrict__ bsum,
    const float* __restrict__ b2, float* __restrict__ out, int N, int E)
{
    int wave = (int)((blockIdx.x * blockDim.x + threadIdx.x) >> 6);
    if (wave >= N) return;
    int node = __builtin_amdgcn_readfirstlane(wave);
    int l = threadIdx.x & 63;
    int g = l >> 4, c = l & 15;
    int rs = rowptr[node] + bsum[node >> 10];
    int re = (node + 1 == N) ? E : rowptr[node + 1] + bsum[(node + 1) >> 10];
    float ad = a_dst2[node];
    float acc = 0.f, sw = 0.f;
    int p = rs + g;
    for (; p + 12 < re; p += 16) {
        int sn0 = csr_rec_i[(size_t)(p     ) * 4];
        int sn1 = csr_rec_i[(size_t)(p +  4) * 4];
        int sn2 = csr_rec_i[(size_t)(p +  8) * 4];
        int sn3 = csr_rec_i[(size_t)(p + 12) * 4];
        float e0 = a_src2[sn0] + ad;
        float e1 = a_src2[sn1] + ad;
        float e2 = a_src2[sn2] + ad;
        float e3 = a_src2[sn3] + ad;
        float x0 = h2[(size_t)sn0 * OUT2 + c];
        float x1 = h2[(size_t)sn1 * OUT2 + c];
        float x2 = h2[(size_t)sn2 * OUT2 + c];
        float x3 = h2[(size_t)sn3 * OUT2 + c];
        e0 = e0 > 0.f ? e0 : 0.2f * e0;
        e1 = e1 > 0.f ? e1 : 0.2f * e1;
        e2 = e2 > 0.f ? e2 : 0.2f * e2;
        e3 = e3 > 0.f ? e3 : 0.2f * e3;
        float w0 = __expf(e0), w1 = __expf(e1), w2 = __expf(e2), w3 = __expf(e3);
        acc = fmaf(w0, x0, acc);
        acc = fmaf(w1, x1, acc);
        acc = fmaf(w2, x2, acc);
        acc = fmaf(w3, x3, acc);
        sw += (w0 + w1) + (w2 + w3);
    }
    for (; p < re; p += 4) {
        int sn = csr_rec_i[(size_t)p * 4];
        float e0 = a_src2[sn] + ad;
        e0 = e0 > 0.f ? e0 : 0.2f * e0;
        float w0 = __expf(e0);
        acc = fmaf(w0, h2[(size_t)sn * OUT2 + c], acc);
        sw += w0;
    }
    acc += __shfl_xor(acc, 16, 64);
    acc += __shfl_xor(acc, 32, 64);
    sw += __shfl_xor(sw, 16, 64);
    sw += __shfl_xor(sw, 32, 64);
    if (l < 16)
        out[(size_t)node * OUT2 + l] = acc / (sw + 1e-16f) + b2[l];
}

extern "C" void kernel_launch(void* const* d_in, const int* in_sizes, int n_in,
                              void* d_out, int out_size, void* d_ws, size_t ws_size,
                              hipStream_t stream)
{
    const float* x        = (const float*)d_in[0];
    const int*   ei       = (const int*)d_in[1];
    const float* W1       = (const float*)d_in[2];
    const float* att_src1 = (const float*)d_in[3];
    const float* att_dst1 = (const float*)d_in[4];
    const float* b1       = (const float*)d_in[5];
    const float* W2       = (const float*)d_in[6];
    const float* att_src2 = (const float*)d_in[7];
    const float* att_dst2 = (const float*)d_in[8];
    const float* b2       = (const float*)d_in[9];
    float* out = (float*)d_out;

    const int N = in_sizes[0] / FIN;
    const int E = in_sizes[1] / 2;
    const int* srcv = ei;
    const int* dstv = ei + E;

    char* base = (char*)d_ws;
    #define ALLOC(ptr, type, nelem) \
        type* ptr = (type*)base; base += (((size_t)(nelem) * sizeof(type) + 255) & ~(size_t)255);
    ALLOC(h1,      unsigned short, (size_t)N * HC)
    ALLOC(csr_rec, uint4,          (size_t)E)
    ALLOC(h2,      float,          (size_t)N * OUT2)
    ALLOC(a_src1v, float,          (size_t)N * 4)
    ALLOC(a_dst1v, float,          (size_t)N * 4)
    ALLOC(a_src2v, float,          (size_t)N)
    ALLOC(a_dst2v, float,          (size_t)N)
    ALLOC(counts,  int,            (size_t)2 * N)      // counts + cursor adjacent
    ALLOC(rowptr,  int,            (size_t)N + 1)
    ALLOC(bsum,    int,            1024)
    #undef ALLOC
    int* cursor = counts + N;
    // W1t (64 KB) aliases the head of csr_rec: live only between w1t_kernel and
    // gemm1_hist_kernel; csr_rec is written later by scatter_kernel.
    unsigned short* W1t = (unsigned short*)csr_rec;

    const int nb = (N + 1023) / 1024;
    const int gemmBlocks = (N + 63) / 64;
    const int histBlocks = (E + 255) / 256;

    (void)hipMemsetAsync(counts, 0, sizeof(int) * 2 * (size_t)N, stream);

    w1t_kernel<<<128, 256, 0, stream>>>(W1, W1t);
    gemm1_hist_kernel<<<gemmBlocks + histBlocks, 256, 0, stream>>>(
        x, W1t, att_src1, att_dst1, h1, a_src1v, a_dst1v, N, gemmBlocks,
        dstv, counts, E);
    scan1_kernel<<<nb, 1024, 0, stream>>>(counts, rowptr, bsum, N);
    scan2_kernel<<<1, 1024, 0, stream>>>(bsum, nb);
    scatter_kernel<<<histBlocks, 256, 0, stream>>>(srcv, dstv, rowptr, bsum, cursor,
                                                   a_src1v, a_dst1v, csr_rec, E);
    agg1_kernel<<<(N + 3) / 4, 256, 0, stream>>>(h1, csr_rec, rowptr, bsum, b1, W2,
                                                 att_src2, att_dst2,
                                                 h2, a_src2v, a_dst2v, N, E);
    agg2_kernel<<<(N + 3) / 4, 256, 0, stream>>>(h2, (const int*)csr_rec,
                                                 a_src2v, a_dst2v, rowptr, bsum,
                                                 b2, out, N, E);
}